// Round 5
// baseline (8543.000 us; speedup 1.0000x reference)
//
#include <hip/hip_runtime.h>
#include <math.h>

#define NN 16384
#define DD 1024
#define HH 4096
#define EE 8
#define OUTD 4096

typedef unsigned short u16;
typedef short v8s __attribute__((ext_vector_type(8)));
typedef float v4f __attribute__((ext_vector_type(4)));

__device__ __forceinline__ u16 f2bf(float f) {
    unsigned int u = __float_as_uint(f);
    u = (u + 0x7fffu + ((u >> 16) & 1u)) >> 16;
    return (u16)u;
}

// async global->LDS, 16B per lane; LDS dest = wave-uniform base + lane*16
__device__ __forceinline__ void cp16(const u16* g, u16* l) {
    __builtin_amdgcn_global_load_lds(
        (const __attribute__((address_space(1))) unsigned int*)g,
        (__attribute__((address_space(3))) unsigned int*)l, 16, 0, 0);
}

// ---------------------------------------------------------------------------
// elementwise f32 -> bf16 (float4 vectorized)
__global__ __launch_bounds__(256) void cvt_bf16(const float* __restrict__ in,
                                                u16* __restrict__ out, int n4) {
    int i = blockIdx.x * 256 + threadIdx.x;
    if (i < n4) {
        float4 v = ((const float4*)in)[i];
        ushort4 o;
        o.x = f2bf(v.x); o.y = f2bf(v.y); o.z = f2bf(v.z); o.w = f2bf(v.w);
        ((ushort4*)out)[i] = o;
    }
}

// ---------------------------------------------------------------------------
// transpose + cast: in [rows][cols] f32  ->  out [cols][rows] bf16, per blockIdx.z matrix
__global__ __launch_bounds__(256) void transpose_cast(const float* __restrict__ in,
                                                      u16* __restrict__ out,
                                                      int rows, int cols) {
    __shared__ float t[32][33];
    const float* inp = in + (size_t)blockIdx.z * rows * cols;
    u16* outp = out + (size_t)blockIdx.z * rows * cols;
    int c0 = blockIdx.x * 32, r0 = blockIdx.y * 32;
    int tx = threadIdx.x & 31, ty = threadIdx.x >> 5;   // 32 x 8
#pragma unroll
    for (int i = 0; i < 4; ++i)
        t[ty + i * 8][tx] = inp[(size_t)(r0 + ty + i * 8) * cols + c0 + tx];
    __syncthreads();
#pragma unroll
    for (int i = 0; i < 4; ++i)
        outp[(size_t)(c0 + ty + i * 8) * rows + r0 + tx] = f2bf(t[tx][ty + i * 8]);
}

// ---------------------------------------------------------------------------
// Gt[e][d] = sum_j W_in[d][j] * Wg[j][e]   (fp32, exact gate path)
// cvec[e]  = sum_j b_in[j]   * Wg[j][e]
__global__ __launch_bounds__(256) void compute_G(const float* __restrict__ Win,
                                                 const float* __restrict__ Wg,
                                                 const float* __restrict__ b_in,
                                                 float* __restrict__ Gt,
                                                 float* __restrict__ cvec) {
    int wid = (blockIdx.x * 256 + threadIdx.x) >> 6;
    int lane = threadIdx.x & 63;
    if (wid < EE * DD) {
        int e = wid >> 10, d = wid & 1023;
        float s = 0.f;
#pragma unroll
        for (int i = 0; i < DD / 64; ++i) {
            int j = i * 64 + lane;
            s += Win[(size_t)d * DD + j] * Wg[j * EE + e];
        }
#pragma unroll
        for (int m = 32; m >= 1; m >>= 1) s += __shfl_xor(s, m);
        if (lane == 0) Gt[e * DD + d] = s;
    } else if (wid < EE * DD + EE) {
        int e = wid - EE * DD;
        float s = 0.f;
#pragma unroll
        for (int i = 0; i < DD / 64; ++i) {
            int j = i * 64 + lane;
            s += b_in[j] * Wg[j * EE + e];
        }
#pragma unroll
        for (int m = 32; m >= 1; m >>= 1) s += __shfl_xor(s, m);
        if (lane == 0) cvec[e] = s;
    }
}

// ---------------------------------------------------------------------------
// gate: fp32 logits = x@Gt + c, softmax top-2 renorm, build per-expert lists
__global__ __launch_bounds__(256) void gate_kernel(const float* __restrict__ x,
                                                   const float* __restrict__ Gt,
                                                   const float* __restrict__ cvec,
                                                   int* __restrict__ counts,
                                                   int* __restrict__ toklist,
                                                   float* __restrict__ wtlist) {
    int wave = threadIdx.x >> 6, lane = threadIdx.x & 63;
    int t = blockIdx.x * 4 + wave;
    const float* xr = x + (size_t)t * DD;
    float p[EE];
#pragma unroll
    for (int e = 0; e < EE; ++e) p[e] = 0.f;
    for (int it = 0; it < DD / 64; ++it) {
        int d = it * 64 + lane;
        float xv = xr[d];
#pragma unroll
        for (int e = 0; e < EE; ++e) p[e] += xv * Gt[e * DD + d];
    }
#pragma unroll
    for (int e = 0; e < EE; ++e) {
        float v = p[e];
#pragma unroll
        for (int m = 32; m >= 1; m >>= 1) v += __shfl_xor(v, m);
        p[e] = v;
    }
    if (lane == 0) {
        float l[EE];
#pragma unroll
        for (int e = 0; e < EE; ++e) l[e] = p[e] + cvec[e];
        int i0 = 0; float v0 = l[0];
#pragma unroll
        for (int e = 1; e < EE; ++e) if (l[e] > v0) { v0 = l[e]; i0 = e; }
        int i1 = -1; float v1 = -1e30f;
#pragma unroll
        for (int e = 0; e < EE; ++e) if (e != i0 && l[e] > v1) { v1 = l[e]; i1 = e; }
        float e1 = __expf(v1 - v0);            // e0 = 1
        float inv = 1.f / (1.f + e1);
        float w0 = inv, w1 = e1 * inv;
        int pos0 = atomicAdd(&counts[i0], 1);
        toklist[i0 * NN + pos0] = t; wtlist[i0 * NN + pos0] = w0;
        int pos1 = atomicAdd(&counts[i1], 1);
        toklist[i1 * NN + pos1] = t; wtlist[i1 * NN + pos1] = w1;
    }
}

__global__ void offsets_kernel(const int* __restrict__ counts, int* __restrict__ offs) {
    if (threadIdx.x == 0) {
        int a = 0;
        for (int e = 0; e < EE; ++e) { offs[e] = a; a += counts[e]; }
    }
}

// ---------------------------------------------------------------------------
// gemm_bt: C[M-tiles x N] = A[M,K] (k-contig) x Bt[N,K] (k-contig)
// 256x256 tile, BK=32, 8 waves (2M x 4N), per-wave 128x64 = acc[8][4],
// 32 MFMA + 12 ds_read_b128 per wave per K-step.
// 2-deep LDS pipeline (distance-1 prefetch, counted vmcnt(4), never drained
// mid-loop) -> LDS 64KB -> 2 blocks/CU = 16 waves/CU, restoring the
// cross-block overlap R4's 3-deep/96KB (1 block/CU, occ 17%) destroyed.
// XOR chunk-swizzled LDS (0 bank conflicts), setprio around MFMA cluster.
// XCD-aware ordering (mode-specific, both bijective, `if constexpr`):
//   modes 1/3 (A small, N wide): by-STRIPE; modes 0/2 (A large): bx-CHUNK.
// MODE 0: +bias        -> bf16 store        (h = x@W_in + b_in)
// MODE 1: gather A rows by token list, +bias, relu -> bf16 store at slot rows (he)
// MODE 2: A = he slot rows, +bias, *gate weight, atomicAdd scatter to moe_f32 (ye)
// MODE 3: plain -> fp32 store (head)
template <int MODE, int K, int LDC>
__global__ __launch_bounds__(512, 4) void gemm_bt(
    const u16* __restrict__ A, const u16* __restrict__ Btb,
    u16* __restrict__ outb, float* __restrict__ outf,
    const float* __restrict__ biasb,
    const int* __restrict__ toklist, const float* __restrict__ wtlist,
    const int* __restrict__ counts, const int* __restrict__ offsets,
    float* __restrict__ moe) {
    __shared__ __align__(16) u16 As[2][256 * 32];   // double-buffered K-tiles
    __shared__ __align__(16) u16 Bs[2][256 * 32];   // total LDS 64KB -> 2 blocks/CU

    constexpr int GX = (MODE == 1 || MODE == 2) ? EE * 64 : NN / 256;
    constexpr int GY = LDC / 256;

    const int wg = blockIdx.x + GX * blockIdx.y;
    const int c = wg & 7;          // XCD (round-robin dispatch assumption)
    const int q = wg >> 3;         // index within this XCD's chunk
    int bx, by;
    if constexpr (MODE == 0 || MODE == 2) {
        constexpr int CW = GX / 8;
        static_assert(GX % 8 == 0, "bx-chunk needs GX%8==0");
        bx = c * CW + q / GY;
        by = q % GY;
    } else {
        constexpr int SH = GY / 8;
        static_assert(GY % 8 == 0, "by-stripe needs GY%8==0");
        bx = q / SH;
        by = c * SH + q % SH;
    }

    int e = 0, mt = bx, cnt = 0, ofs = 0;
    if (MODE == 1 || MODE == 2) {
        e = bx >> 6; mt = bx & 63;
        cnt = counts[e];
        if (mt * 256 >= cnt) return;
        ofs = offsets[e];
    }
    const int m0 = mt * 256;
    const int n0 = by * 256;

    const u16* Bt = Btb;
    const float* bias = biasb;
    if (MODE == 1) { Bt += (size_t)e * HH * DD; bias += e * HH; }
    if (MODE == 2) { Bt += (size_t)e * DD * HH; bias += e * DD; }

    const int lane = threadIdx.x & 63;
    const int wave = threadIdx.x >> 6;     // 0..7
    const int rl = lane >> 2;              // row within a 16-row staging slot
    const int kc = lane & 3;               // 16B chunk within 64B row
    // write-side XOR swizzle: LDS dest stays linear (global_load_lds rule),
    // global source chunk is permuted so data lands swizzled.
    const int kcs = kc ^ ((rl >> 1) & 3);

    const u16* aS[2];
    const u16* bS[2];
#pragma unroll
    for (int s = 0; s < 2; ++s) {
        int trow = wave * 32 + s * 16 + rl;   // tile row 0..255
        long arow;
        if (MODE == 1) {
            int rr = m0 + trow; if (rr >= cnt) rr = cnt - 1;
            arow = toklist[e * NN + rr];
        } else if (MODE == 2) {
            int rr = m0 + trow; if (rr >= cnt) rr = cnt - 1;
            arow = ofs + rr;
        } else {
            arow = m0 + trow;
        }
        aS[s] = A + (size_t)arow * K + kcs * 8;
        bS[s] = Bt + (size_t)(n0 + trow) * K + kcs * 8;
    }
    u16* aL[2] = { &As[0][(wave * 32) * 32], &As[0][(wave * 32 + 16) * 32] };
    u16* bL[2] = { &Bs[0][(wave * 32) * 32], &Bs[0][(wave * 32 + 16) * 32] };

    const int wm = wave & 1, wn = wave >> 1;   // 2 x 4 wave grid
    const int fr = lane & 15;
    // read-side XOR swizzle: same involution of the 16B chunk index
    const int kswz = ((lane >> 4) ^ ((fr >> 1) & 3)) * 8;

    v4f acc[8][4];
#pragma unroll
    for (int i = 0; i < 8; ++i)
#pragma unroll
        for (int j = 0; j < 4; ++j)
#pragma unroll
            for (int c2 = 0; c2 < 4; ++c2) acc[i][j][c2] = 0.f;

    auto STAGE = [&](int kt, int buf) {
#pragma unroll
        for (int s = 0; s < 2; ++s) {
            cp16(aS[s] + kt * 32, aL[s] + buf * 8192);
            cp16(bS[s] + kt * 32, bL[s] + buf * 8192);
        }
    };

    constexpr int NIT = K / 32;
    // prologue: tile 0 in flight (4 cp16 per thread)
    STAGE(0, 0);

    int cur = 0;
    for (int it = 0; it < NIT; ++it) {
        if (it + 1 < NIT) {
            STAGE(it + 1, cur ^ 1);
            // 8 outstanding; wait until oldest 4 (tile `it`) landed,
            // tile `it+1`'s 4 stay in flight across MFMA + both barriers
            asm volatile("s_waitcnt vmcnt(4)" ::: "memory");
        } else {
            asm volatile("s_waitcnt vmcnt(0)" ::: "memory");
        }
        __builtin_amdgcn_s_barrier();          // all waves' tile-`it` staging done
        asm volatile("" ::: "memory");         // keep ds_reads below the barrier

        v8s af[8], bv[4];
#pragma unroll
        for (int i = 0; i < 8; ++i)
            af[i] = *(const v8s*)&As[cur][(wm * 128 + i * 16 + fr) * 32 + kswz];
#pragma unroll
        for (int j = 0; j < 4; ++j)
            bv[j] = *(const v8s*)&Bs[cur][(wn * 64 + j * 16 + fr) * 32 + kswz];

        __builtin_amdgcn_s_setprio(1);
#pragma unroll
        for (int i = 0; i < 8; ++i)
#pragma unroll
            for (int j = 0; j < 4; ++j)
                acc[i][j] = __builtin_amdgcn_mfma_f32_16x16x32_bf16(af[i], bv[j], acc[i][j], 0, 0, 0);
        __builtin_amdgcn_s_setprio(0);

        asm volatile("" ::: "memory");         // keep ds_reads above the barrier
        __builtin_amdgcn_s_barrier();          // all reads of buf[cur] consumed
        cur ^= 1;
    }

    const int quad = (lane >> 4) * 4;
#pragma unroll
    for (int i = 0; i < 8; ++i) {
#pragma unroll
        for (int r = 0; r < 4; ++r) {
            int rloc = wm * 128 + i * 16 + quad + r;
            int grow = m0 + rloc;
            if ((MODE == 1 || MODE == 2) && grow >= cnt) continue;
            int tok = 0; float wgt = 0.f;
            if (MODE == 2) { tok = toklist[e * NN + grow]; wgt = wtlist[e * NN + grow]; }
#pragma unroll
            for (int j = 0; j < 4; ++j) {
                int col = n0 + wn * 64 + j * 16 + fr;
                float v = acc[i][j][r];
                if (MODE == 0) {
                    outb[(size_t)grow * LDC + col] = f2bf(v + bias[col]);
                } else if (MODE == 1) {
                    float t = v + bias[col];
                    t = t > 0.f ? t : 0.f;
                    outb[(size_t)(ofs + grow) * LDC + col] = f2bf(t);
                } else if (MODE == 2) {
                    atomicAdd(&moe[(size_t)tok * LDC + col], wgt * (v + bias[col]));
                } else {
                    outf[(size_t)grow * LDC + col] = v;
                }
            }
        }
    }
}

// ---------------------------------------------------------------------------
extern "C" void kernel_launch(void* const* d_in, const int* in_sizes, int n_in,
                              void* d_out, int out_size, void* d_ws, size_t ws_size,
                              hipStream_t stream) {
    const float* x    = (const float*)d_in[0];
    const float* Win  = (const float*)d_in[1];
    const float* b_in = (const float*)d_in[2];
    const float* Wg   = (const float*)d_in[3];
    const float* W1   = (const float*)d_in[4];
    const float* b1   = (const float*)d_in[5];
    const float* W2   = (const float*)d_in[6];
    const float* b2   = (const float*)d_in[7];
    const float* Wh   = (const float*)d_in[8];
    float* out = (float*)d_out;

    // workspace layout (256B aligned)
    char* p = (char*)d_ws;
    size_t off = 0;
    auto alloc = [&](size_t bytes) {
        char* r = p + off;
        off = (off + bytes + 255) & ~(size_t)255;
        return r;
    };
    u16*   x_bf   = (u16*)alloc((size_t)NN * DD * 2);
    u16*   wint   = (u16*)alloc((size_t)DD * DD * 2);
    u16*   w1t    = (u16*)alloc((size_t)EE * DD * HH * 2);
    u16*   w2t    = (u16*)alloc((size_t)EE * DD * HH * 2);
    u16*   wht    = (u16*)alloc((size_t)DD * OUTD * 2);
    u16*   h_bf   = (u16*)alloc((size_t)NN * DD * 2);
    float* moe_f  = (float*)alloc((size_t)NN * DD * 4);
    u16*   moe_bf = (u16*)alloc((size_t)NN * DD * 2);
    float* Gt     = (float*)alloc((size_t)EE * DD * 4);
    float* cvec   = (float*)alloc(256);
    int*   counts = (int*)alloc(256);
    int*   offs   = (int*)alloc(256);
    int*   tok    = (int*)alloc((size_t)EE * NN * 4);
    float* wt     = (float*)alloc((size_t)EE * NN * 4);
    if (off > ws_size) return;  // workspace too small — fail loudly via wrong output

    u16* he = (u16*)d_out;  // 2N x H bf16 == exactly out_size*4 bytes; head GEMM overwrites

    hipMemsetAsync(counts, 0, 256, stream);
    hipMemsetAsync(moe_f, 0, (size_t)NN * DD * 4, stream);

    // conversions / transposes
    cvt_bf16<<<dim3(NN * DD / 4 / 256), 256, 0, stream>>>(x, x_bf, NN * DD / 4);
    transpose_cast<<<dim3(DD / 32, DD / 32, 1), 256, 0, stream>>>(Win, wint, DD, DD);
    transpose_cast<<<dim3(HH / 32, DD / 32, EE), 256, 0, stream>>>(W1, w1t, DD, HH);
    transpose_cast<<<dim3(DD / 32, HH / 32, EE), 256, 0, stream>>>(W2, w2t, HH, DD);
    transpose_cast<<<dim3(OUTD / 32, DD / 32, 1), 256, 0, stream>>>(Wh, wht, DD, OUTD);
    compute_G<<<dim3((EE * DD + EE) / 4), 256, 0, stream>>>(Win, Wg, b_in, Gt, cvec);

    // h = x@W_in + b_in  (bf16 out)
    gemm_bt<0, DD, DD><<<dim3(NN / 256, DD / 256), 512, 0, stream>>>(
        x_bf, wint, h_bf, nullptr, b_in, nullptr, nullptr, nullptr, nullptr, nullptr);

    // routing (exact fp32 logits)
    gate_kernel<<<dim3(NN / 4), 256, 0, stream>>>(x, Gt, cvec, counts, tok, wt);
    offsets_kernel<<<dim3(1), 64, 0, stream>>>(counts, offs);

    // he = relu(h_gathered @ W1[e] + b1[e])  -> bf16 slots in d_out
    gemm_bt<1, DD, HH><<<dim3(EE * 64, HH / 256), 512, 0, stream>>>(
        h_bf, w1t, he, nullptr, b1, tok, wt, counts, offs, nullptr);

    // moe += w * (he @ W2[e] + b2[e])  (atomic fp32 scatter)
    gemm_bt<2, HH, DD><<<dim3(EE * 64, DD / 256), 512, 0, stream>>>(
        he, w2t, nullptr, nullptr, b2, tok, wt, counts, offs, moe_f);

    cvt_bf16<<<dim3(NN * DD / 4 / 256), 256, 0, stream>>>(moe_f, moe_bf, NN * DD / 4);

    // out = moe @ W_head  (fp32 store)
    gemm_bt<3, DD, OUTD><<<dim3(NN / 256, OUTD / 256), 512, 0, stream>>>(
        moe_bf, wht, nullptr, out, nullptr, nullptr, nullptr, nullptr, nullptr, nullptr);
}

// Round 6
// 2177.159 us; speedup vs baseline: 3.9239x; 3.9239x over previous
//
#include <hip/hip_runtime.h>
#include <math.h>

#define NN 16384
#define DD 1024
#define HH 4096
#define EE 8
#define OUTD 4096

typedef unsigned short u16;
typedef short v8s __attribute__((ext_vector_type(8)));
typedef float v4f __attribute__((ext_vector_type(4)));

__device__ __forceinline__ u16 f2bf(float f) {
    unsigned int u = __float_as_uint(f);
    u = (u + 0x7fffu + ((u >> 16) & 1u)) >> 16;
    return (u16)u;
}

// async global->LDS, 16B per lane; LDS dest = wave-uniform base + lane*16
__device__ __forceinline__ void cp16(const u16* g, u16* l) {
    __builtin_amdgcn_global_load_lds(
        (const __attribute__((address_space(1))) unsigned int*)g,
        (__attribute__((address_space(3))) unsigned int*)l, 16, 0, 0);
}

// ---------------------------------------------------------------------------
// elementwise f32 -> bf16 (float4 vectorized)
__global__ __launch_bounds__(256) void cvt_bf16(const float* __restrict__ in,
                                                u16* __restrict__ out, int n4) {
    int i = blockIdx.x * 256 + threadIdx.x;
    if (i < n4) {
        float4 v = ((const float4*)in)[i];
        ushort4 o;
        o.x = f2bf(v.x); o.y = f2bf(v.y); o.z = f2bf(v.z); o.w = f2bf(v.w);
        ((ushort4*)out)[i] = o;
    }
}

// ---------------------------------------------------------------------------
// transpose + cast: in [rows][cols] f32  ->  out [cols][rows] bf16, per blockIdx.z matrix
__global__ __launch_bounds__(256) void transpose_cast(const float* __restrict__ in,
                                                      u16* __restrict__ out,
                                                      int rows, int cols) {
    __shared__ float t[32][33];
    const float* inp = in + (size_t)blockIdx.z * rows * cols;
    u16* outp = out + (size_t)blockIdx.z * rows * cols;
    int c0 = blockIdx.x * 32, r0 = blockIdx.y * 32;
    int tx = threadIdx.x & 31, ty = threadIdx.x >> 5;   // 32 x 8
#pragma unroll
    for (int i = 0; i < 4; ++i)
        t[ty + i * 8][tx] = inp[(size_t)(r0 + ty + i * 8) * cols + c0 + tx];
    __syncthreads();
#pragma unroll
    for (int i = 0; i < 4; ++i)
        outp[(size_t)(c0 + ty + i * 8) * rows + r0 + tx] = f2bf(t[tx][ty + i * 8]);
}

// ---------------------------------------------------------------------------
// Gt[e][d] = sum_j W_in[d][j] * Wg[j][e]   (fp32, exact gate path)
// cvec[e]  = sum_j b_in[j]   * Wg[j][e]
__global__ __launch_bounds__(256) void compute_G(const float* __restrict__ Win,
                                                 const float* __restrict__ Wg,
                                                 const float* __restrict__ b_in,
                                                 float* __restrict__ Gt,
                                                 float* __restrict__ cvec) {
    int wid = (blockIdx.x * 256 + threadIdx.x) >> 6;
    int lane = threadIdx.x & 63;
    if (wid < EE * DD) {
        int e = wid >> 10, d = wid & 1023;
        float s = 0.f;
#pragma unroll
        for (int i = 0; i < DD / 64; ++i) {
            int j = i * 64 + lane;
            s += Win[(size_t)d * DD + j] * Wg[j * EE + e];
        }
#pragma unroll
        for (int m = 32; m >= 1; m >>= 1) s += __shfl_xor(s, m);
        if (lane == 0) Gt[e * DD + d] = s;
    } else if (wid < EE * DD + EE) {
        int e = wid - EE * DD;
        float s = 0.f;
#pragma unroll
        for (int i = 0; i < DD / 64; ++i) {
            int j = i * 64 + lane;
            s += b_in[j] * Wg[j * EE + e];
        }
#pragma unroll
        for (int m = 32; m >= 1; m >>= 1) s += __shfl_xor(s, m);
        if (lane == 0) cvec[e] = s;
    }
}

// ---------------------------------------------------------------------------
// gate: fp32 logits = x@Gt + c, softmax top-2 renorm, build per-expert lists
__global__ __launch_bounds__(256) void gate_kernel(const float* __restrict__ x,
                                                   const float* __restrict__ Gt,
                                                   const float* __restrict__ cvec,
                                                   int* __restrict__ counts,
                                                   int* __restrict__ toklist,
                                                   float* __restrict__ wtlist) {
    int wave = threadIdx.x >> 6, lane = threadIdx.x & 63;
    int t = blockIdx.x * 4 + wave;
    const float* xr = x + (size_t)t * DD;
    float p[EE];
#pragma unroll
    for (int e = 0; e < EE; ++e) p[e] = 0.f;
    for (int it = 0; it < DD / 64; ++it) {
        int d = it * 64 + lane;
        float xv = xr[d];
#pragma unroll
        for (int e = 0; e < EE; ++e) p[e] += xv * Gt[e * DD + d];
    }
#pragma unroll
    for (int e = 0; e < EE; ++e) {
        float v = p[e];
#pragma unroll
        for (int m = 32; m >= 1; m >>= 1) v += __shfl_xor(v, m);
        p[e] = v;
    }
    if (lane == 0) {
        float l[EE];
#pragma unroll
        for (int e = 0; e < EE; ++e) l[e] = p[e] + cvec[e];
        int i0 = 0; float v0 = l[0];
#pragma unroll
        for (int e = 1; e < EE; ++e) if (l[e] > v0) { v0 = l[e]; i0 = e; }
        int i1 = -1; float v1 = -1e30f;
#pragma unroll
        for (int e = 0; e < EE; ++e) if (e != i0 && l[e] > v1) { v1 = l[e]; i1 = e; }
        float e1 = __expf(v1 - v0);            // e0 = 1
        float inv = 1.f / (1.f + e1);
        float w0 = inv, w1 = e1 * inv;
        int pos0 = atomicAdd(&counts[i0], 1);
        toklist[i0 * NN + pos0] = t; wtlist[i0 * NN + pos0] = w0;
        int pos1 = atomicAdd(&counts[i1], 1);
        toklist[i1 * NN + pos1] = t; wtlist[i1 * NN + pos1] = w1;
    }
}

__global__ void offsets_kernel(const int* __restrict__ counts, int* __restrict__ offs) {
    if (threadIdx.x == 0) {
        int a = 0;
        for (int e = 0; e < EE; ++e) { offs[e] = a; a += counts[e]; }
    }
}

// ---------------------------------------------------------------------------
// gemm_bt: C[M-tiles x N] = A[M,K] (k-contig) x Bt[N,K] (k-contig)
// 256x256 tile, BK=64, 8 waves (2M x 4N), per-wave 128x64 = acc[8][4].
// ONE s_barrier + ONE counted vmcnt(8) per 64-MFMA-per-wave K-tile (4x less
// sync than R4's 2-barrier BK=32): 2 LDS buffers (128KB, 1 block/CU), prologue
// stages tile0, each iteration stages tile it+1 into buf^1 AFTER the barrier
// (whose readers all passed the top barrier), then vmcnt(8) gates tile-it's
// 8 loads. launch_bounds(512,2) -- (512,4) spilled acc to scratch in R5
// (VGPR 64, 6.5GB scratch writes); 2 waves/SIMD is the only spill-free choice
// for this geometry.
// LDS layout [256 rows][8 chunks of 16B], XOR-swizzled: linear slot (row,c)
// holds global chunk c^(row&7); write side pre-swizzles global source
// ((tid&7)^((tid>>3)&7)), read side XORs chunk with fr&7 -> 2-way max (free).
// XCD-aware ordering (mode-specific, bijective, if constexpr):
//   modes 1/3 (A small, N wide): by-STRIPE; modes 0/2 (A large): bx-CHUNK.
// MODE 0: +bias -> bf16 | 1: gather,+bias,relu -> bf16 slots | 2: +bias,*wgt,
// atomicAdd scatter fp32 | 3: plain -> fp32
template <int MODE, int K, int LDC>
__global__ __launch_bounds__(512, 2) void gemm_bt(
    const u16* __restrict__ A, const u16* __restrict__ Btb,
    u16* __restrict__ outb, float* __restrict__ outf,
    const float* __restrict__ biasb,
    const int* __restrict__ toklist, const float* __restrict__ wtlist,
    const int* __restrict__ counts, const int* __restrict__ offsets,
    float* __restrict__ moe) {
    __shared__ __align__(16) u16 As[2][256 * 64];   // 2 x 32KB
    __shared__ __align__(16) u16 Bs[2][256 * 64];   // total 128KB -> 1 block/CU

    constexpr int GX = (MODE == 1 || MODE == 2) ? EE * 64 : NN / 256;
    constexpr int GY = LDC / 256;

    const int wg = blockIdx.x + GX * blockIdx.y;
    const int c = wg & 7;          // XCD (round-robin dispatch assumption)
    const int q = wg >> 3;         // index within this XCD's chunk
    int bx, by;
    if constexpr (MODE == 0 || MODE == 2) {
        constexpr int CW = GX / 8;
        static_assert(GX % 8 == 0, "bx-chunk needs GX%8==0");
        bx = c * CW + q / GY;
        by = q % GY;
    } else {
        constexpr int SH = GY / 8;
        static_assert(GY % 8 == 0, "by-stripe needs GY%8==0");
        bx = q / SH;
        by = c * SH + q % SH;
    }

    int e = 0, mt = bx, cnt = 0, ofs = 0;
    if (MODE == 1 || MODE == 2) {
        e = bx >> 6; mt = bx & 63;
        cnt = counts[e];
        if (mt * 256 >= cnt) return;
        ofs = offsets[e];
    }
    const int m0 = mt * 256;
    const int n0 = by * 256;

    const u16* Bt = Btb;
    const float* bias = biasb;
    if (MODE == 1) { Bt += (size_t)e * HH * DD; bias += e * HH; }
    if (MODE == 2) { Bt += (size_t)e * DD * HH; bias += e * DD; }

    const int tid = threadIdx.x;
    const int lane = tid & 63;
    const int wave = tid >> 6;             // 0..7
    // staging map: per part s (0..3), linear chunk idx = s*512 + tid
    //   row-in-tile = idx>>3 = s*64 + (tid>>3), lds chunk = idx&7 = tid&7
    // swizzle: linear slot (row, cl) receives global chunk cl^(row&7)
    const int srcswz = (tid & 7) ^ ((tid >> 3) & 7);

    const u16* aS[4];
    const u16* bS[4];
#pragma unroll
    for (int s = 0; s < 4; ++s) {
        int trow = s * 64 + (tid >> 3);   // tile row 0..255
        long arow;
        if (MODE == 1) {
            int rr = m0 + trow; if (rr >= cnt) rr = cnt - 1;
            arow = toklist[e * NN + rr];
        } else if (MODE == 2) {
            int rr = m0 + trow; if (rr >= cnt) rr = cnt - 1;
            arow = ofs + rr;
        } else {
            arow = m0 + trow;
        }
        aS[s] = A + (size_t)arow * K + srcswz * 8;
        bS[s] = Bt + (size_t)(n0 + trow) * K + srcswz * 8;
    }

    const int wm = wave & 1, wn = wave >> 1;   // 2 x 4 wave grid
    const int fr = lane & 15;
    const int qv = lane >> 4;                  // 0..3: k-quarter within 32-k window

    v4f acc[8][4];
#pragma unroll
    for (int i = 0; i < 8; ++i)
#pragma unroll
        for (int j = 0; j < 4; ++j)
#pragma unroll
            for (int c2 = 0; c2 < 4; ++c2) acc[i][j][c2] = 0.f;

    auto STAGE = [&](int kt, int buf) {       // 8 cp16: full 256x64 A and B tile
#pragma unroll
        for (int s = 0; s < 4; ++s) {
            cp16(aS[s] + kt * 64, &As[buf][(s * 512 + wave * 64) * 8]);
            cp16(bS[s] + kt * 64, &Bs[buf][(s * 512 + wave * 64) * 8]);
        }
    };

    constexpr int NIT = K / 64;
    STAGE(0, 0);                              // prologue: tile 0 in flight

    int cur = 0;
    for (int it = 0; it < NIT; ++it) {
        // top barrier: all waves finished reading buf[cur^1] (tile it-1),
        // so staging tile it+1 into it is safe.
        asm volatile("" ::: "memory");
        __builtin_amdgcn_s_barrier();
        asm volatile("" ::: "memory");

        if (it + 1 < NIT) {
            STAGE(it + 1, cur ^ 1);
            // 8 new outstanding; wait until only those 8 remain ->
            // all of tile `it`'s loads have landed.
            asm volatile("s_waitcnt vmcnt(8)" ::: "memory");
        } else {
            asm volatile("s_waitcnt vmcnt(0)" ::: "memory");
        }

        // 4 phases: kk = p&1 selects 32-k window, ih = (p>>1)*4 selects i-half
#pragma unroll
        for (int p = 0; p < 4; ++p) {
            const int kk = p & 1;
            const int ih = (p >> 1) * 4;
            const int ch = ((kk << 2) + qv);
            v8s af2[4], bv2[4];
#pragma unroll
            for (int i2 = 0; i2 < 4; ++i2) {
                int row = wm * 128 + (ih + i2) * 16 + fr;
                af2[i2] = *(const v8s*)&As[cur][row * 64 + (ch ^ (fr & 7)) * 8];
            }
#pragma unroll
            for (int j = 0; j < 4; ++j) {
                int row = wn * 64 + j * 16 + fr;
                bv2[j] = *(const v8s*)&Bs[cur][row * 64 + (ch ^ (fr & 7)) * 8];
            }
            __builtin_amdgcn_s_setprio(1);
#pragma unroll
            for (int i2 = 0; i2 < 4; ++i2)
#pragma unroll
                for (int j = 0; j < 4; ++j)
                    acc[ih + i2][j] = __builtin_amdgcn_mfma_f32_16x16x32_bf16(
                        af2[i2], bv2[j], acc[ih + i2][j], 0, 0, 0);
            __builtin_amdgcn_s_setprio(0);
        }
        cur ^= 1;
    }

    const int quad = (lane >> 4) * 4;
#pragma unroll
    for (int i = 0; i < 8; ++i) {
#pragma unroll
        for (int r = 0; r < 4; ++r) {
            int rloc = wm * 128 + i * 16 + quad + r;
            int grow = m0 + rloc;
            if ((MODE == 1 || MODE == 2) && grow >= cnt) continue;
            int tok = 0; float wgt = 0.f;
            if (MODE == 2) { tok = toklist[e * NN + grow]; wgt = wtlist[e * NN + grow]; }
#pragma unroll
            for (int j = 0; j < 4; ++j) {
                int col = n0 + wn * 64 + j * 16 + fr;
                float v = acc[i][j][r];
                if (MODE == 0) {
                    outb[(size_t)grow * LDC + col] = f2bf(v + bias[col]);
                } else if (MODE == 1) {
                    float t = v + bias[col];
                    t = t > 0.f ? t : 0.f;
                    outb[(size_t)(ofs + grow) * LDC + col] = f2bf(t);
                } else if (MODE == 2) {
                    atomicAdd(&moe[(size_t)tok * LDC + col], wgt * (v + bias[col]));
                } else {
                    outf[(size_t)grow * LDC + col] = v;
                }
            }
        }
    }
}

// ---------------------------------------------------------------------------
extern "C" void kernel_launch(void* const* d_in, const int* in_sizes, int n_in,
                              void* d_out, int out_size, void* d_ws, size_t ws_size,
                              hipStream_t stream) {
    const float* x    = (const float*)d_in[0];
    const float* Win  = (const float*)d_in[1];
    const float* b_in = (const float*)d_in[2];
    const float* Wg   = (const float*)d_in[3];
    const float* W1   = (const float*)d_in[4];
    const float* b1   = (const float*)d_in[5];
    const float* W2   = (const float*)d_in[6];
    const float* b2   = (const float*)d_in[7];
    const float* Wh   = (const float*)d_in[8];
    float* out = (float*)d_out;

    // workspace layout (256B aligned)
    char* p = (char*)d_ws;
    size_t off = 0;
    auto alloc = [&](size_t bytes) {
        char* r = p + off;
        off = (off + bytes + 255) & ~(size_t)255;
        return r;
    };
    u16*   x_bf   = (u16*)alloc((size_t)NN * DD * 2);
    u16*   wint   = (u16*)alloc((size_t)DD * DD * 2);
    u16*   w1t    = (u16*)alloc((size_t)EE * DD * HH * 2);
    u16*   w2t    = (u16*)alloc((size_t)EE * DD * HH * 2);
    u16*   wht    = (u16*)alloc((size_t)DD * OUTD * 2);
    u16*   h_bf   = (u16*)alloc((size_t)NN * DD * 2);
    float* moe_f  = (float*)alloc((size_t)NN * DD * 4);
    u16*   moe_bf = (u16*)alloc((size_t)NN * DD * 2);
    float* Gt     = (float*)alloc((size_t)EE * DD * 4);
    float* cvec   = (float*)alloc(256);
    int*   counts = (int*)alloc(256);
    int*   offs   = (int*)alloc(256);
    int*   tok    = (int*)alloc((size_t)EE * NN * 4);
    float* wt     = (float*)alloc((size_t)EE * NN * 4);
    if (off > ws_size) return;  // workspace too small — fail loudly via wrong output

    u16* he = (u16*)d_out;  // 2N x H bf16 == exactly out_size*4 bytes; head GEMM overwrites

    hipMemsetAsync(counts, 0, 256, stream);
    hipMemsetAsync(moe_f, 0, (size_t)NN * DD * 4, stream);

    // conversions / transposes
    cvt_bf16<<<dim3(NN * DD / 4 / 256), 256, 0, stream>>>(x, x_bf, NN * DD / 4);
    transpose_cast<<<dim3(DD / 32, DD / 32, 1), 256, 0, stream>>>(Win, wint, DD, DD);
    transpose_cast<<<dim3(HH / 32, DD / 32, EE), 256, 0, stream>>>(W1, w1t, DD, HH);
    transpose_cast<<<dim3(DD / 32, HH / 32, EE), 256, 0, stream>>>(W2, w2t, HH, DD);
    transpose_cast<<<dim3(OUTD / 32, DD / 32, 1), 256, 0, stream>>>(Wh, wht, DD, OUTD);
    compute_G<<<dim3((EE * DD + EE) / 4), 256, 0, stream>>>(Win, Wg, b_in, Gt, cvec);

    // h = x@W_in + b_in  (bf16 out)
    gemm_bt<0, DD, DD><<<dim3(NN / 256, DD / 256), 512, 0, stream>>>(
        x_bf, wint, h_bf, nullptr, b_in, nullptr, nullptr, nullptr, nullptr, nullptr);

    // routing (exact fp32 logits)
    gate_kernel<<<dim3(NN / 4), 256, 0, stream>>>(x, Gt, cvec, counts, tok, wt);
    offsets_kernel<<<dim3(1), 64, 0, stream>>>(counts, offs);

    // he = relu(h_gathered @ W1[e] + b1[e])  -> bf16 slots in d_out
    gemm_bt<1, DD, HH><<<dim3(EE * 64, HH / 256), 512, 0, stream>>>(
        h_bf, w1t, he, nullptr, b1, tok, wt, counts, offs, nullptr);

    // moe += w * (he @ W2[e] + b2[e])  (atomic fp32 scatter)
    gemm_bt<2, HH, DD><<<dim3(EE * 64, DD / 256), 512, 0, stream>>>(
        he, w2t, nullptr, nullptr, b2, tok, wt, counts, offs, moe_f);

    cvt_bf16<<<dim3(NN * DD / 4 / 256), 256, 0, stream>>>(moe_f, moe_bf, NN * DD / 4);

    // out = moe @ W_head  (fp32 store)
    gemm_bt<3, DD, OUTD><<<dim3(NN / 256, OUTD / 256), 512, 0, stream>>>(
        moe_bf, wht, nullptr, out, nullptr, nullptr, nullptr, nullptr, nullptr, nullptr);
}